// Round 17
// baseline (250.020 us; speedup 1.0000x reference)
//
#include <hip/hip_runtime.h>
#include <cstdint>

#define B_ 8
#define N_ 512
#define M_ 512
#define D_ 512
#define F_ 512
#define H_ 8
#define DH_ 64
#define FH_ 64

typedef __attribute__((ext_vector_type(8))) short bf16x8;
typedef __attribute__((ext_vector_type(4))) float f32x4;
typedef __attribute__((ext_vector_type(8))) unsigned short u16x8;

// RNE float -> bf16 bits, and back
__device__ __forceinline__ unsigned short f2bf(float x) {
    unsigned u = __float_as_uint(x);
    return (unsigned short)((u + 0x7fffu + ((u >> 16) & 1u)) >> 16);
}
__device__ __forceinline__ float bf2f(unsigned short b) {
    return __uint_as_float(((unsigned)b) << 16);
}

// Nontemporal loads via clang ext_vector_type. Keep zero-reuse W2/W1 streams
// out of cache.
__device__ __forceinline__ f32x4 ntload4(const float* p) {
    return __builtin_nontemporal_load((const f32x4*)p);
}
__device__ __forceinline__ float ntload1(const float* p) {
    return __builtin_nontemporal_load(p);
}

// DPP-based partial reduce (VALU pipe). bound_ctrl=true.
template <int CTRL>
__device__ __forceinline__ float dpp_add(float x) {
    int y = __builtin_amdgcn_update_dpp(0, __float_as_int(x), CTRL, 0xf, 0xf, true);
    return x + __int_as_float(y);
}

// Fused K1+K2+K3: per (h, n-pair): Q1=gelu(X*diag(W1)); logits=Q1*W2^T;
// softmax -> pbf (bf16 in LDS); PV via MFMA-GEMV: A-op = Vt tile (rows=f,
// k=m), B-op = p broadcast to all 16 cols (col 0 read out). A never touches
// HBM. h = bid&7 pins each head's 512KB Vt slice to one XCD's L2.
__global__ __launch_bounds__(256, 4) void syn_k_attn_pv(const float* __restrict__ X,
                                                        const float* __restrict__ W1,
                                                        const float* __restrict__ W2,
                                                        const unsigned short* __restrict__ Vthi,
                                                        const float* __restrict__ WV,
                                                        unsigned short* __restrict__ Yhi,
                                                        unsigned short* __restrict__ Ylo) {
    int bid = blockIdx.x;
    int h = bid & 7;
    int n0 = (bid >> 3) * 2;
    int t = threadIdx.x;
    int wave = t >> 6, lane = t & 63;
    __shared__ float q1s[2][8 * 68];                      // [nq][b][d]
    __shared__ float logits[8 * 520];                     // f32, reused per nq
    __shared__ __align__(16) unsigned short pbf[2][8 * 512];  // softmax probs bf16

    // Phase 1: Q1 for both n's
    {
        int d = t & 63, b0 = t >> 6;
        #pragma unroll
        for (int nq = 0; nq < 2; ++nq) {
            int n = n0 + nq;
            int hn = h * 512 + n;
            float w = ntload1(W1 + (size_t)hn * (DH_ * DH_) + d * (DH_ + 1));
            #pragma unroll
            for (int i = 0; i < 2; ++i) {
                int bi = b0 + i * 4;
                float x = X[((size_t)(bi * N_ + n)) * D_ + h * DH_ + d];
                float v = x * w;
                q1s[nq][bi * 68 + d] = 0.5f * v * (1.0f + erff(v * 0.70710678118654752440f));
            }
        }
    }
    __syncthreads();

    // Phase 2+3 per nq: logits (nt W2 stream, DPP reduce) then softmax -> pbf
    int mr = lane >> 3, c = lane & 7;
    #pragma unroll 1
    for (int nq = 0; nq < 2; ++nq) {
        int hn = h * 512 + n0 + nq;
        float4 qa[8], qb[8];
        #pragma unroll
        for (int b = 0; b < 8; ++b) {
            qa[b] = *(const float4*)&q1s[nq][b * 68 + c * 8];
            qb[b] = *(const float4*)&q1s[nq][b * 68 + c * 8 + 4];
        }
        const float* w2 = W2 + (size_t)hn * ((size_t)M_ * DH_);
        #pragma unroll 4
        for (int g = 0; g < 16; ++g) {
            int m = (wave + g * 4) * 8 + mr;
            const float* wr = w2 + (size_t)m * DH_ + c * 8;
            f32x4 wa = ntload4(wr);
            f32x4 wb = ntload4(wr + 4);
            float acc[8];
            #pragma unroll
            for (int b = 0; b < 8; ++b) {
                float a0 = wa.x * qa[b].x + wa.y * qa[b].y + wa.z * qa[b].z + wa.w * qa[b].w
                         + wb.x * qb[b].x + wb.y * qb[b].y + wb.z * qb[b].z + wb.w * qb[b].w;
                a0 = dpp_add<0xB1>(a0);    // + lane^1 (quad_perm)
                a0 = dpp_add<0x4E>(a0);    // + lane^2 (quad_perm)
                a0 = dpp_add<0x124>(a0);   // row_ror:4 — valid on (lane%16)<4 i.e. c<4
                acc[b] = a0;
            }
            float lo = c == 0 ? acc[0] : c == 1 ? acc[1] : c == 2 ? acc[2] : acc[3];
            float hi = c == 0 ? acc[4] : c == 1 ? acc[5] : c == 2 ? acc[6] : acc[7];
            if (c < 4) {
                logits[c * 520 + m] = lo;
                logits[(c + 4) * 520 + m] = hi;
            }
        }
        __syncthreads();

        for (int bb = wave; bb < 8; bb += 4) {
            const float* lrow = &logits[bb * 520 + lane * 8];
            float4 va = *(const float4*)lrow;
            float4 vb = *(const float4*)(lrow + 4);
            float v[8] = {va.x, va.y, va.z, va.w, vb.x, vb.y, vb.z, vb.w};
            float mx = v[0];
            #pragma unroll
            for (int i = 1; i < 8; ++i) mx = fmaxf(mx, v[i]);
            #pragma unroll
            for (int s = 1; s < 64; s <<= 1) mx = fmaxf(mx, __shfl_xor(mx, s));
            float e[8]; float sum = 0.f;
            #pragma unroll
            for (int i = 0; i < 8; ++i) { e[i] = expf(v[i] - mx); sum += e[i]; }
            #pragma unroll
            for (int s = 1; s < 64; s <<= 1) sum += __shfl_xor(sum, s);
            float inv = 1.0f / sum;
            unsigned short hb[8];
            #pragma unroll
            for (int i = 0; i < 8; ++i) hb[i] = f2bf(e[i] * inv);
            *(u16x8*)&pbf[nq][bb * 512 + lane * 8] = *(u16x8*)hb;
        }
        __syncthreads();
    }

    // Phase 4: PV. wave = f-tile (16 f's). Per (b, nq): C[f][*] = sum_m
    // Vt[f][m] * p[m] — B replicated across cols, col 0 valid everywhere.
    int ft = wave;
    int frow = lane & 15, kg = lane >> 4;
    float sv[4];
    #pragma unroll
    for (int r = 0; r < 4; ++r)
        sv[r] = WV[(size_t)h * (FH_ * FH_) + (ft * 16 + kg * 4 + r) * (FH_ + 1)];

    #pragma unroll
    for (int b2 = 0; b2 < 2; ++b2) {
        f32x4 acc[4][2];
        #pragma unroll
        for (int b4 = 0; b4 < 4; ++b4)
            #pragma unroll
            for (int q = 0; q < 2; ++q)
                acc[b4][q] = (f32x4){0.f, 0.f, 0.f, 0.f};

        #pragma unroll
        for (int b4 = 0; b4 < 4; ++b4) {
            int b = b2 * 4 + b4;
            const unsigned short* vt = Vthi
                + ((size_t)((b * 8 + h) * 64 + ft * 16 + frow)) * 512 + kg * 8;
            const unsigned short* p0 = &pbf[0][b * 512 + kg * 8];
            const unsigned short* p1 = &pbf[1][b * 512 + kg * 8];
            #pragma unroll 4
            for (int ks = 0; ks < 16; ++ks) {
                bf16x8 av  = *(const bf16x8*)(vt + ks * 32);
                bf16x8 pb0 = *(const bf16x8*)(p0 + ks * 32);
                bf16x8 pb1 = *(const bf16x8*)(p1 + ks * 32);
                acc[b4][0] = __builtin_amdgcn_mfma_f32_16x16x32_bf16(av, pb0, acc[b4][0], 0, 0, 0);
                acc[b4][1] = __builtin_amdgcn_mfma_f32_16x16x32_bf16(av, pb1, acc[b4][1], 0, 0, 0);
            }
        }
        if (frow == 0) {
            #pragma unroll
            for (int b4 = 0; b4 < 4; ++b4)
                #pragma unroll
                for (int nq = 0; nq < 2; ++nq)
                    #pragma unroll
                    for (int r = 0; r < 4; ++r) {
                        int f = ft * 16 + kg * 4 + r;
                        float y = acc[b4][nq][r] * sv[r];
                        unsigned short hbb = f2bf(y);
                        unsigned short lbb = f2bf(y - bf2f(hbb));
                        int b = b2 * 4 + b4;
                        size_t base = ((size_t)(b * N_ + n0 + nq)) * F_ + h * FH_ + f;
                        Yhi[base] = hbb;
                        Ylo[base] = lbb;
                    }
        }
    }
}

// Split Ow into bf16 hi/lo arrays. 512*512 elems, 4/thread, grid 256.
__global__ __launch_bounds__(256) void syn_k_splitw(const float* __restrict__ Ow,
                                                    unsigned short* __restrict__ Whi,
                                                    unsigned short* __restrict__ Wlo) {
    int i = (blockIdx.x * 256 + threadIdx.x) * 4;
    float4 v = *(const float4*)(Ow + i);
    float vv[4] = {v.x, v.y, v.z, v.w};
    unsigned short hb[4], lb[4];
    #pragma unroll
    for (int j = 0; j < 4; ++j) {
        hb[j] = f2bf(vv[j]);
        lb[j] = f2bf(vv[j] - bf2f(hb[j]));
    }
    uint2 hv, lv;
    hv.x = (unsigned)hb[0] | ((unsigned)hb[1] << 16);
    hv.y = (unsigned)hb[2] | ((unsigned)hb[3] << 16);
    lv.x = (unsigned)lb[0] | ((unsigned)lb[1] << 16);
    lv.y = (unsigned)lb[2] | ((unsigned)lb[3] << 16);
    *(uint2*)(Whi + i) = hv;
    *(uint2*)(Wlo + i) = lv;
}

// splitv: Vt_hi[(bh*64+f)*512 + m] = bf16(V[b][m][h*64+f]). LDS transpose.
__global__ __launch_bounds__(256) void syn_k_splitv(const float* __restrict__ V,
                                                    unsigned short* __restrict__ Vthi) {
    int bh = blockIdx.x;
    int b = bh >> 3, h = bh & 7;
    int t = threadIdx.x;
    __shared__ float lds[64 * 68];
    for (int m0 = 0; m0 < M_; m0 += 64) {
        int m = t >> 2, fo = (t & 3) * 16;
        const float* src = V + ((size_t)(b * M_ + m0 + m)) * F_ + h * FH_ + fo;
        #pragma unroll
        for (int i = 0; i < 4; ++i)
            *(float4*)&lds[m * 68 + fo + i * 4] = *(const float4*)(src + i * 4);
        __syncthreads();
        int f = t >> 2, mo = (t & 3) * 16;
        unsigned short hb[16];
        #pragma unroll
        for (int i = 0; i < 16; ++i)
            hb[i] = f2bf(lds[(mo + i) * 68 + f]);
        size_t base = ((size_t)(bh * 64 + f)) * 512 + m0 + mo;
        *(u16x8*)(Vthi + base) = *(u16x8*)hb;
        *(u16x8*)(Vthi + base + 8) = *(u16x8*)&hb[8];
        __syncthreads();
    }
}

// K4 (split-bf16 MFMA): out = Yhi·Whi^T + Yhi·Wlo^T + Ylo·Whi^T + Ob.
__global__ __launch_bounds__(256) void syn_k_out_mfma(const unsigned short* __restrict__ Yhi,
                                                      const unsigned short* __restrict__ Ylo,
                                                      const unsigned short* __restrict__ Whi,
                                                      const unsigned short* __restrict__ Wlo,
                                                      const float* __restrict__ Ob,
                                                      float* __restrict__ out) {
    int r0 = blockIdx.x * 64;
    int f0 = blockIdx.y * 64;
    int t = threadIdx.x;
    int lane = t & 63, wave = t >> 6;
    int wr = wave >> 1, wc = wave & 1;
    __shared__ __align__(16) unsigned short Alh[64 * 64], All[64 * 64];
    __shared__ __align__(16) unsigned short Blh[64 * 64], Bll[64 * 64];
    f32x4 acc[2][2];
    #pragma unroll
    for (int i = 0; i < 2; ++i)
        #pragma unroll
        for (int j = 0; j < 2; ++j) acc[i][j] = (f32x4){0.f, 0.f, 0.f, 0.f};

    int srow = t >> 3, skg = t & 7;
    int sslot = skg ^ (srow & 7);

    #pragma unroll 1
    for (int kb = 0; kb < 512; kb += 64) {
        #pragma unroll
        for (int rr = 0; rr < 2; ++rr) {
            int row = srow + rr * 32;
            size_t ya = (size_t)(r0 + row) * 512 + kb + skg * 8;
            size_t wa = (size_t)(f0 + row) * 512 + kb + skg * 8;
            *(u16x8*)&Alh[row * 64 + sslot * 8] = *(const u16x8*)(Yhi + ya);
            *(u16x8*)&All[row * 64 + sslot * 8] = *(const u16x8*)(Ylo + ya);
            *(u16x8*)&Blh[row * 64 + sslot * 8] = *(const u16x8*)(Whi + wa);
            *(u16x8*)&Bll[row * 64 + sslot * 8] = *(const u16x8*)(Wlo + wa);
        }
        __syncthreads();
        #pragma unroll
        for (int mg = 0; mg < 2; ++mg) {
            int kslot = (mg * 4 + (lane >> 4)) ^ (lane & 7);
            bf16x8 afh[2], afl[2], bfh[2], bfl[2];
            #pragma unroll
            for (int q = 0; q < 2; ++q) {
                int arow = wr * 32 + q * 16 + (lane & 15);
                afh[q] = *(const bf16x8*)&Alh[arow * 64 + kslot * 8];
                afl[q] = *(const bf16x8*)&All[arow * 64 + kslot * 8];
                int brow = wc * 32 + q * 16 + (lane & 15);
                bfh[q] = *(const bf16x8*)&Blh[brow * 64 + kslot * 8];
                bfl[q] = *(const bf16x8*)&Bll[brow * 64 + kslot * 8];
            }
            #pragma unroll
            for (int i = 0; i < 2; ++i)
                #pragma unroll
                for (int j = 0; j < 2; ++j) {
                    acc[i][j] = __builtin_amdgcn_mfma_f32_16x16x32_bf16(afh[i], bfh[j], acc[i][j], 0, 0, 0);
                    acc[i][j] = __builtin_amdgcn_mfma_f32_16x16x32_bf16(afh[i], bfl[j], acc[i][j], 0, 0, 0);
                    acc[i][j] = __builtin_amdgcn_mfma_f32_16x16x32_bf16(afl[i], bfh[j], acc[i][j], 0, 0, 0);
                }
        }
        __syncthreads();
    }

    int crow = r0 + wr * 32 + (lane >> 4) * 4;
    int ccol = f0 + wc * 32 + (lane & 15);
    float ob0 = Ob[ccol], ob1 = Ob[ccol + 16];
    #pragma unroll
    for (int i = 0; i < 2; ++i)
        #pragma unroll
        for (int j = 0; j < 2; ++j) {
            float obv = (j == 0) ? ob0 : ob1;
            #pragma unroll
            for (int r = 0; r < 4; ++r) {
                int row = crow + i * 16 + r;
                out[(size_t)row * F_ + ccol + j * 16] = acc[i][j][r] + obv;
            }
        }
}

extern "C" void kernel_launch(void* const* d_in, const int* in_sizes, int n_in,
                              void* d_out, int out_size, void* d_ws, size_t ws_size,
                              hipStream_t stream) {
    const float* X  = (const float*)d_in[0];
    const float* V  = (const float*)d_in[1];
    const float* W1 = (const float*)d_in[2];
    const float* W2 = (const float*)d_in[3];
    const float* WV = (const float*)d_in[4];
    const float* Ow = (const float*)d_in[5];
    const float* Ob = (const float*)d_in[6];
    float* out = (float*)d_out;

    unsigned short* Yhi = (unsigned short*)d_ws;          // B*N*F u16
    unsigned short* Ylo = Yhi + (size_t)B_ * N_ * F_;
    unsigned short* Whi = Ylo + (size_t)B_ * N_ * F_;
    unsigned short* Wlo = Whi + (size_t)F_ * F_;
    unsigned short* Vthi = Wlo + (size_t)F_ * F_;

    syn_k_splitw<<<(F_ * F_) / (256 * 4), 256, 0, stream>>>(Ow, Whi, Wlo);
    syn_k_splitv<<<B_ * H_, 256, 0, stream>>>(V, Vthi);
    syn_k_attn_pv<<<(H_ * N_) / 2, 256, 0, stream>>>(X, W1, W2, Vthi, WV, Yhi, Ylo);
    syn_k_out_mfma<<<dim3((B_ * N_) / 64, F_ / 64), 256, 0, stream>>>(Yhi, Ylo, Whi, Wlo, Ob, out);
}